// Round 1
// 7889.425 us; speedup vs baseline: 1.5624x; 1.5624x over previous
//
#include <hip/hip_runtime.h>
#include <stdint.h>

#define NLAYER 12
#define NH 12
#define DH 64
#define DMODEL 768
#define DI 3072
#define NV 10000
#define QLEN 512
#define MLEN 512
#define CLEN 32
#define BSZ 4
#define KLEN (CLEN + MLEN + QLEN)   // 1056
#define MQ (QLEN * BSZ)             // 2048
#define MK (KLEN * BSZ)             // 4224
#define H3 (3 * NH * DH)            // 2304
#define HD (NH * DH)                // 768
#define NG (BSZ * NH)               // 48 batched-attention groups
#define SROW ((size_t)QLEN * KLEN)  // score elems per group: 512*1056
#define KPAD_R 1152                 // rbuf rows padded to 9*128
#define NPAD_V 10112                // proj cols padded to 79*128

typedef __bf16 bf16;
typedef __bf16 bf16x8 __attribute__((ext_vector_type(8)));
typedef float f32x4 __attribute__((ext_vector_type(4)));

// async global -> LDS, 16B per lane (dest must be linear: wave base + lane*16)
__device__ __forceinline__ void gload16(const void* g, void* l) {
    __builtin_amdgcn_global_load_lds((const __attribute__((address_space(1))) void*)g,
                                     (__attribute__((address_space(3))) void*)l, 16, 0, 0);
}

// x = hi + lo split store (hi = RNE bf16(x); lo = bf16(x - hi))
__device__ __forceinline__ void split_store(float x, bf16* __restrict__ hp,
                                            bf16* __restrict__ lp, size_t off) {
    bf16 h = (bf16)x;
    hp[off] = h;
    lp[off] = (bf16)(x - (float)h);
}

// ---------------- embedding: h = emb[x] * sqrt(D) ----------------
__global__ __launch_bounds__(256) void k_embed(const int* __restrict__ x,
                                               const float* __restrict__ emb,
                                               float* __restrict__ h) {
    int idx = blockIdx.x * 256 + threadIdx.x;
    if (idx >= MQ * DMODEL) return;
    int row = idx / DMODEL;
    int d = idx % DMODEL;
    int tok = x[row];
    h[idx] = emb[(size_t)tok * DMODEL + d] * 27.712812921102035f;  // sqrt(768)
}

// ---------------- sinusoidal position embedding -> bf16 hi/lo planes [KPAD_R][D] ------------
__global__ __launch_bounds__(256) void k_posemb(bf16* __restrict__ rh, bf16* __restrict__ rl) {
    int idx = blockIdx.x * 256 + threadIdx.x;
    if (idx >= KPAD_R * DMODEL) return;
    int k = idx / DMODEL;
    int d = idx % DMODEL;
    float v = 0.0f;
    if (k < KLEN) {
        int pos = KLEN - 1 - k;
        int j = (d < DMODEL / 2) ? d : d - DMODEL / 2;
        double inv = exp(-((double)(2 * j) / (double)DMODEL) * log(10000.0));
        double s = (double)pos * inv;
        v = (d < DMODEL / 2) ? (float)sin(s) : (float)cos(s);
    }
    split_store(v, rh, rl, (size_t)idx);
}

// ---------------- concat [condition; mems[l]; h] -> bf16 hi/lo planes ----------------
__global__ __launch_bounds__(256) void k_concat(const float* __restrict__ cond,
                                                const float* __restrict__ mem_l,
                                                const float* __restrict__ h,
                                                bf16* __restrict__ catH,
                                                bf16* __restrict__ catL) {
    int idx = blockIdx.x * 256 + threadIdx.x;
    if (idx >= MK * DMODEL) return;
    int row = idx / DMODEL;
    int k = row / BSZ;
    float v;
    if (k < CLEN) v = cond[idx];
    else if (k < CLEN + MLEN) v = mem_l[idx - CLEN * BSZ * DMODEL];
    else v = h[idx - (CLEN + MLEN) * BSZ * DMODEL];
    split_store(v, catH, catL, (size_t)idx);
}

// ---------------- weight transpose + split: W[K][N] fp32 -> Bt_hi/lo[Npad][K] bf16 ----------
// grid (Npad/32, K/32); rows n >= N zero-filled so GEMM staging needs no guards.
__global__ __launch_bounds__(256) void k_wconv(const float* __restrict__ W,
                                               bf16* __restrict__ Bh,
                                               bf16* __restrict__ Bl,
                                               int K, int N) {
    __shared__ float t[32][33];
    int n0 = blockIdx.x * 32, k0 = blockIdx.y * 32;
    int tc = threadIdx.x & 31, tr = threadIdx.x >> 5;  // 8 rows per pass
#pragma unroll
    for (int i = 0; i < 32; i += 8) {
        int n = n0 + tc;
        t[tr + i][tc] = (n < N) ? W[(size_t)(k0 + tr + i) * N + n] : 0.0f;
    }
    __syncthreads();
#pragma unroll
    for (int i = 0; i < 32; i += 8) {
        int n = n0 + tr + i;
        int k = k0 + tc;
        float x = t[tc][tr + i];
        size_t off = (size_t)n * K + k;
        bf16 h = (bf16)x;
        Bh[off] = h;
        Bl[off] = (bf16)(x - (float)h);
    }
}

// ---------------- split-bf16 MFMA GEMM: C[M,N] = A[M,K] @ B^T[N,K] (+bias)(+relu) -----------
// A as hi/lo planes [Mpad][K], B as hi/lo planes [Npad][K] (Mpad,Npad multiples of 128,
// K multiple of 32, padded regions zero). acc += Ah*Bh + Ah*Bl + Al*Bh (fp32 MFMA accum).
// 128x128 tile, 4 waves as 2x2, each wave 4x4 fragments of 16x16x32. LDS 32KB.
template <bool BIAS, bool RELU, bool SPLITOUT>
__global__ __launch_bounds__(256) void k_mgemm(const bf16* __restrict__ Ahi,
                                               const bf16* __restrict__ Alo,
                                               const bf16* __restrict__ Bhi,
                                               const bf16* __restrict__ Blo,
                                               const float* __restrict__ bias,
                                               float* __restrict__ C,
                                               bf16* __restrict__ Chi,
                                               bf16* __restrict__ Clo,
                                               int M, int N, int K, int ldc) {
    __shared__ __align__(16) bf16 As[2][128][32];
    __shared__ __align__(16) bf16 Bs[2][128][32];
    int tid = threadIdx.x;
    int lane = tid & 63;
    int wave = tid >> 6;
    int bm = blockIdx.y * 128, bn = blockIdx.x * 128;
    int wr = (wave >> 1) * 64, wc = (wave & 1) * 64;
    int fr = lane & 15;
    int fk = (lane >> 4) * 8;

    const f32x4 fzero = {0.f, 0.f, 0.f, 0.f};
    f32x4 acc[4][4];
#pragma unroll
    for (int i = 0; i < 4; i++)
#pragma unroll
        for (int j = 0; j < 4; j++) acc[i][j] = fzero;

    // staging chunk assignment: chunk c (16B) -> LDS byte offset c*16 == [c>>2][(c&3)*8]
    int c0 = tid, c1 = tid + 256;
    int r0 = c0 >> 2, p0 = (c0 & 3) * 8;
    int r1 = c1 >> 2, p1 = (c1 & 3) * 8;
    size_t gA0 = (size_t)(bm + r0) * K + p0;
    size_t gA1 = (size_t)(bm + r1) * K + p1;
    size_t gB0 = (size_t)(bn + r0) * K + p0;
    size_t gB1 = (size_t)(bn + r1) * K + p1;

    for (int k0 = 0; k0 < K; k0 += 32) {
        gload16(Ahi + gA0 + k0, &As[0][r0][p0]);
        gload16(Ahi + gA1 + k0, &As[0][r1][p1]);
        gload16(Alo + gA0 + k0, &As[1][r0][p0]);
        gload16(Alo + gA1 + k0, &As[1][r1][p1]);
        gload16(Bhi + gB0 + k0, &Bs[0][r0][p0]);
        gload16(Bhi + gB1 + k0, &Bs[0][r1][p1]);
        gload16(Blo + gB0 + k0, &Bs[1][r0][p0]);
        gload16(Blo + gB1 + k0, &Bs[1][r1][p1]);
        __syncthreads();  // compiler drains vmcnt before s_barrier

        bf16x8 ah[4], al[4], bh[4], bl[4];
#pragma unroll
        for (int mi = 0; mi < 4; mi++) {
            ah[mi] = *(const bf16x8*)&As[0][wr + mi * 16 + fr][fk];
            al[mi] = *(const bf16x8*)&As[1][wr + mi * 16 + fr][fk];
        }
#pragma unroll
        for (int ni = 0; ni < 4; ni++) {
            bh[ni] = *(const bf16x8*)&Bs[0][wc + ni * 16 + fr][fk];
            bl[ni] = *(const bf16x8*)&Bs[1][wc + ni * 16 + fr][fk];
        }
#pragma unroll
        for (int mi = 0; mi < 4; mi++)
#pragma unroll
            for (int ni = 0; ni < 4; ni++) {
                acc[mi][ni] = __builtin_amdgcn_mfma_f32_16x16x32_bf16(ah[mi], bh[ni], acc[mi][ni], 0, 0, 0);
                acc[mi][ni] = __builtin_amdgcn_mfma_f32_16x16x32_bf16(ah[mi], bl[ni], acc[mi][ni], 0, 0, 0);
                acc[mi][ni] = __builtin_amdgcn_mfma_f32_16x16x32_bf16(al[mi], bh[ni], acc[mi][ni], 0, 0, 0);
            }
        __syncthreads();
    }

    // epilogue: C/D layout col=lane&15, row=(lane>>4)*4+reg (m89/m91-verified)
#pragma unroll
    for (int mi = 0; mi < 4; mi++) {
        int rowb = bm + wr + mi * 16 + (lane >> 4) * 4;
#pragma unroll
        for (int ni = 0; ni < 4; ni++) {
            int col = bn + wc + ni * 16 + fr;
            if (col >= N) continue;
            float bv = BIAS ? bias[col] : 0.0f;
#pragma unroll
            for (int r = 0; r < 4; r++) {
                int row = rowb + r;
                if (row >= M) continue;
                float xv = acc[mi][ni][r] + bv;
                if (RELU) xv = fmaxf(xv, 0.0f);
                size_t off = (size_t)row * ldc + col;
                if (SPLITOUT) {
                    bf16 hh = (bf16)xv;
                    Chi[off] = hh;
                    Clo[off] = (bf16)(xv - (float)hh);
                } else {
                    C[off] = xv;
                }
            }
        }
    }
}

// ---------------- q prep: qw = q + r_w_bias, qr = q + r_r_bias ----------------
__global__ __launch_bounds__(256) void k_qprep(const float* __restrict__ heads,
                                               const float* __restrict__ rwb,
                                               const float* __restrict__ rrb,
                                               float* __restrict__ qw,
                                               float* __restrict__ qr) {
    int idx = blockIdx.x * 256 + threadIdx.x;
    if (idx >= NG * QLEN * DH) return;
    int g = idx >> 15;
    int rem = idx & 32767;
    int i = rem >> 6;
    int d = rem & 63;
    int b = g / NH, n = g % NH;
    float q = heads[((size_t)((CLEN + MLEN + i) * BSZ + b)) * H3 + n * DH + d];
    qw[idx] = q + rwb[n * DH + d];
    qr[idx] = q + rrb[n * DH + d];
}

// ---------------- batched NT GEMM over attention groups (fp32, unchanged) ----------------
template <bool SHIFT_ACC>
__global__ __launch_bounds__(256) void k_bgemm_nt(const float* __restrict__ A, int lda, int sAb, int sAn,
                                                  const float* __restrict__ B, int ldb, int sBb, int sBn,
                                                  float* __restrict__ C,
                                                  int M, int N, int K) {
    int g = blockIdx.z;
    int b = g / NH, n = g % NH;
    A += (size_t)b * sAb + (size_t)n * sAn;
    B += (size_t)b * sBb + (size_t)n * sBn;
    C += (size_t)g * SROW;
    __shared__ float As[16][64];
    __shared__ float Bs[16][64];
    int tid = threadIdx.x;
    int bm = blockIdx.y * 64, bn = blockIdx.x * 64;
    int ty = tid >> 4, tx = tid & 15;
    float acc[4][4] = {};
    int arow = tid >> 2, ak = (tid & 3) * 4;
    for (int k0 = 0; k0 < K; k0 += 16) {
        float4 av = make_float4(0.f, 0.f, 0.f, 0.f);
        if (bm + arow < M) av = *(const float4*)(A + (size_t)(bm + arow) * lda + k0 + ak);
        float4 bv = make_float4(0.f, 0.f, 0.f, 0.f);
        if (bn + arow < N) bv = *(const float4*)(B + (size_t)(bn + arow) * ldb + k0 + ak);
        As[ak + 0][arow] = av.x; As[ak + 1][arow] = av.y;
        As[ak + 2][arow] = av.z; As[ak + 3][arow] = av.w;
        Bs[ak + 0][arow] = bv.x; Bs[ak + 1][arow] = bv.y;
        Bs[ak + 2][arow] = bv.z; Bs[ak + 3][arow] = bv.w;
        __syncthreads();
#pragma unroll
        for (int kk = 0; kk < 16; kk++) {
            float a[4], bb[4];
#pragma unroll
            for (int t = 0; t < 4; t++) a[t] = As[kk][ty * 4 + t];
#pragma unroll
            for (int t = 0; t < 4; t++) bb[t] = Bs[kk][tx * 4 + t];
#pragma unroll
            for (int ii = 0; ii < 4; ii++)
#pragma unroll
                for (int jj = 0; jj < 4; jj++)
                    acc[ii][jj] += a[ii] * bb[jj];
        }
        __syncthreads();
    }
#pragma unroll
    for (int ii = 0; ii < 4; ii++) {
        int m = bm + ty * 4 + ii;
        if (m >= M) continue;
#pragma unroll
        for (int jj = 0; jj < 4; jj++) {
            int nn = bn + tx * 4 + jj;
            if (nn >= N) continue;
            if (SHIFT_ACC) {
                int j = nn - (QLEN - 1) + m;
                if (j >= 0) C[(size_t)m * KLEN + j] += acc[ii][jj];
            } else {
                C[(size_t)m * KLEN + nn] = acc[ii][jj];
            }
        }
    }
}

// ---------------- masked softmax over scores, in place; zero masked tail ----------------
__global__ __launch_bounds__(256) void k_softmax(float* __restrict__ sA) {
    __shared__ float red[256];
    int i = blockIdx.x;
    int g = blockIdx.y;
    int tid = threadIdx.x;
    float* row = sA + (size_t)g * SROW + (size_t)i * KLEN;
    int len = i + CLEN + MLEN + 1;
    float v[5];
    int cnt = 0;
    float mx = -1e30f;
    for (int j = tid; j < len; j += 256) {
        float s = row[j] * 0.125f;
        v[cnt++] = s;
        mx = fmaxf(mx, s);
    }
    red[tid] = mx;
    __syncthreads();
    for (int st = 128; st > 0; st >>= 1) {
        if (tid < st) red[tid] = fmaxf(red[tid], red[tid + st]);
        __syncthreads();
    }
    float smax = red[0];
    __syncthreads();
    float sum = 0.f;
    cnt = 0;
    for (int j = tid; j < len; j += 256) {
        float e = __expf(v[cnt] - smax);
        v[cnt] = e;
        sum += e;
        cnt++;
    }
    red[tid] = sum;
    __syncthreads();
    for (int st = 128; st > 0; st >>= 1) {
        if (tid < st) red[tid] += red[tid + st];
        __syncthreads();
    }
    float inv = 1.0f / red[0];
    cnt = 0;
    for (int j = tid; j < len; j += 256) row[j] = v[cnt++] * inv;
    for (int j = tid; j < KLEN; j += 256)
        if (j >= len) row[j] = 0.0f;
}

// ---------------- batched AV GEMM: attnb = P @ V, output as bf16 hi/lo planes ------------
__global__ __launch_bounds__(256) void k_av_gemm(const float* __restrict__ P,
                                                 const float* __restrict__ heads,
                                                 bf16* __restrict__ atH,
                                                 bf16* __restrict__ atL) {
    int g = blockIdx.z;
    int b = g / NH, n = g % NH;
    const float* Ap = P + (size_t)g * SROW;
    const float* Bp = heads + (size_t)b * H3 + 2 * HD + n * DH;
    bf16* Ch = atH + (size_t)b * HD + n * DH;
    bf16* Cl = atL + (size_t)b * HD + n * DH;
    __shared__ float As[16][33];
    __shared__ float Bs[16][64];
    int tid = threadIdx.x;
    int bm = blockIdx.y * 32;
    int ty = tid >> 4, tx = tid & 15;
    float acc[2][4] = {};
    int arow = tid >> 3, ak = (tid & 7) * 2;
    int bk = tid >> 4, bc = (tid & 15) * 4;
    for (int k0 = 0; k0 < KLEN; k0 += 16) {
        float2 av = *(const float2*)(Ap + (size_t)(bm + arow) * KLEN + k0 + ak);
        float4 bv = *(const float4*)(Bp + (size_t)(k0 + bk) * (BSZ * H3) + bc);
        As[ak + 0][arow] = av.x;
        As[ak + 1][arow] = av.y;
        Bs[bk][bc + 0] = bv.x; Bs[bk][bc + 1] = bv.y;
        Bs[bk][bc + 2] = bv.z; Bs[bk][bc + 3] = bv.w;
        __syncthreads();
#pragma unroll
        for (int kk = 0; kk < 16; kk++) {
            float a0 = As[kk][ty * 2 + 0];
            float a1 = As[kk][ty * 2 + 1];
            float bb[4];
#pragma unroll
            for (int t = 0; t < 4; t++) bb[t] = Bs[kk][tx * 4 + t];
#pragma unroll
            for (int t = 0; t < 4; t++) {
                acc[0][t] += a0 * bb[t];
                acc[1][t] += a1 * bb[t];
            }
        }
        __syncthreads();
    }
#pragma unroll
    for (int ii = 0; ii < 2; ii++) {
        int m = bm + ty * 2 + ii;
#pragma unroll
        for (int jj = 0; jj < 4; jj++) {
            int nn = tx * 4 + jj;
            size_t off = (size_t)m * (BSZ * HD) + nn;
            float xv = acc[ii][jj];
            bf16 hh = (bf16)xv;
            Ch[off] = hh;
            Cl[off] = (bf16)(xv - (float)hh);
        }
    }
}

// ---------------- h = LN(h + delta); also emit bf16 hi/lo planes of h ----------------
__global__ __launch_bounds__(256) void k_add_ln(float* __restrict__ h,
                                                const float* __restrict__ delta,
                                                const float* __restrict__ g,
                                                const float* __restrict__ bta,
                                                bf16* __restrict__ hH,
                                                bf16* __restrict__ hL) {
    __shared__ float xs[DMODEL];
    __shared__ float red[256];
    int row = blockIdx.x;
    int tid = threadIdx.x;
    float* hr = h + (size_t)row * DMODEL;
    const float* dr = delta + (size_t)row * DMODEL;
    float s = 0.f;
    for (int d = tid; d < DMODEL; d += 256) {
        float v = hr[d] + dr[d];
        xs[d] = v;
        s += v;
    }
    red[tid] = s;
    __syncthreads();
    for (int st = 128; st > 0; st >>= 1) {
        if (tid < st) red[tid] += red[tid + st];
        __syncthreads();
    }
    float mean = red[0] * (1.0f / DMODEL);
    __syncthreads();
    float v2 = 0.f;
    for (int d = tid; d < DMODEL; d += 256) {
        float t = xs[d] - mean;
        v2 += t * t;
    }
    red[tid] = v2;
    __syncthreads();
    for (int st = 128; st > 0; st >>= 1) {
        if (tid < st) red[tid] += red[tid + st];
        __syncthreads();
    }
    float inv = rsqrtf(red[0] * (1.0f / DMODEL) + 1e-5f);
    for (int d = tid; d < DMODEL; d += 256) {
        float y = (xs[d] - mean) * inv * g[d] + bta[d];
        hr[d] = y;
        split_store(y, hH, hL, (size_t)row * DMODEL + d);
    }
}

extern "C" void kernel_launch(void* const* d_in, const int* in_sizes, int n_in,
                              void* d_out, int out_size, void* d_ws, size_t ws_size,
                              hipStream_t stream) {
    const int* x = (const int*)d_in[0];
    const float* condition = (const float*)d_in[1];
    const float* mems = (const float*)d_in[2];
    const float* emb = (const float*)d_in[3];
    const float* qkv_w = (const float*)d_in[4];
    const float* r_net_w = (const float*)d_in[5];
    const float* o_w = (const float*)d_in[6];
    const float* ln1_g = (const float*)d_in[7];
    const float* ln1_b = (const float*)d_in[8];
    const float* w1 = (const float*)d_in[9];
    const float* b1 = (const float*)d_in[10];
    const float* w2 = (const float*)d_in[11];
    const float* b2 = (const float*)d_in[12];
    const float* ln2_g = (const float*)d_in[13];
    const float* ln2_b = (const float*)d_in[14];
    const float* r_w_bias = (const float*)d_in[15];
    const float* r_r_bias = (const float*)d_in[16];
    const float* proj_w = (const float*)d_in[17];
    const float* proj_b = (const float*)d_in[18];
    float* out = (float*)d_out;

    // ---- workspace layout (fp32 regions) ----
    float* ws = (float*)d_ws;
    float* h = ws;                                    // 2048*768
    float* rk = h + (size_t)MQ * DMODEL;              // 1056*768
    float* heads = rk + (size_t)KLEN * HD;            // 4224*2304
    float* qw = heads + (size_t)MK * H3;              // 48*512*64
    float* qr = qw + (size_t)NG * QLEN * DH;          // 48*512*64
    float* delta = qr + (size_t)NG * QLEN * DH;       // 2048*768
    float* sA = delta + (size_t)MQ * DMODEL;          // 48*512*1056 scores/probs

    // ---- bf16 hi/lo planes aliased INSIDE sA (dead outside bgemm..av window) ----
    // capacity: 51,904,512 bf16 elems; used: 37,748,736
    bf16* BtH = (bf16*)sA;                            // weights^T, max 10112*768
    bf16* BtL = BtH + (size_t)NPAD_V * DMODEL;
    bf16* ffnH = BtL + (size_t)NPAD_V * DMODEL;       // 2048*3072
    bf16* ffnL = ffnH + (size_t)MQ * DI;
    bf16* catH = ffnL + (size_t)MQ * DI;              // 4224*768
    bf16* catL = catH + (size_t)MK * DMODEL;
    bf16* hH = catL + (size_t)MK * DMODEL;            // 2048*768
    bf16* hL = hH + (size_t)MQ * DMODEL;

    // ---- bf16 planes that must survive the sA-live window: placed after sA ----
    float* endf = sA + (size_t)NG * SROW;
    bf16* rbH = (bf16*)endf;                          // 1152*768 (pos emb, whole run)
    bf16* rbL = rbH + (size_t)KPAD_R * DMODEL;
    bf16* atH = rbL + (size_t)KPAD_R * DMODEL;        // 2048*768 (written while sA live)
    bf16* atL = atH + (size_t)MQ * HD;
    // total ws: ~181 MB (<= previous version's 187 MB)

    dim3 blk(256);
    k_embed<<<dim3((MQ * DMODEL + 255) / 256), blk, 0, stream>>>(x, emb, h);
    k_posemb<<<dim3((KPAD_R * DMODEL + 255) / 256), blk, 0, stream>>>(rbH, rbL);

    for (int l = 0; l < NLAYER; l++) {
        k_concat<<<dim3((MK * DMODEL + 255) / 256), blk, 0, stream>>>(
            condition, mems + (size_t)l * MLEN * BSZ * DMODEL, h, catH, catL);

        // heads = cat @ qkv_w[l]    [4224,2304]
        k_wconv<<<dim3(H3 / 32, DMODEL / 32), blk, 0, stream>>>(
            qkv_w + (size_t)l * DMODEL * H3, BtH, BtL, DMODEL, H3);
        k_mgemm<false, false, false><<<dim3(H3 / 128, MK / 128), blk, 0, stream>>>(
            catH, catL, BtH, BtL, nullptr, heads, nullptr, nullptr, MK, H3, DMODEL, H3);

        // rk = r @ r_net_w[l]       [1056,768] (A rows padded to 1152 with zeros)
        k_wconv<<<dim3(HD / 32, DMODEL / 32), blk, 0, stream>>>(
            r_net_w + (size_t)l * DMODEL * HD, BtH, BtL, DMODEL, HD);
        k_mgemm<false, false, false><<<dim3(HD / 128, KPAD_R / 128), blk, 0, stream>>>(
            rbH, rbL, BtH, BtL, nullptr, rk, nullptr, nullptr, KLEN, HD, DMODEL, HD);

        k_qprep<<<dim3((NG * QLEN * DH + 255) / 256), blk, 0, stream>>>(
            heads, r_w_bias, r_r_bias, qw, qr);

        k_bgemm_nt<false><<<dim3((KLEN + 63) / 64, QLEN / 64, NG), blk, 0, stream>>>(
            qw, DH, NH * QLEN * DH, QLEN * DH,
            heads + HD, BSZ * H3, H3, DH,
            sA, QLEN, KLEN, DH);

        k_bgemm_nt<true><<<dim3((KLEN + 63) / 64, QLEN / 64, NG), blk, 0, stream>>>(
            qr, DH, NH * QLEN * DH, QLEN * DH,
            rk, HD, 0, DH,
            sA, QLEN, KLEN, DH);

        k_softmax<<<dim3(QLEN, NG), blk, 0, stream>>>(sA);

        // attnb = P @ V  (emits bf16 hi/lo planes directly)
        k_av_gemm<<<dim3(1, QLEN / 32, NG), blk, 0, stream>>>(sA, heads, atH, atL);

        // delta = attnb @ o_w[l]    [2048,768]
        k_wconv<<<dim3(DMODEL / 32, HD / 32), blk, 0, stream>>>(
            o_w + (size_t)l * HD * DMODEL, BtH, BtL, HD, DMODEL);
        k_mgemm<false, false, false><<<dim3(DMODEL / 128, MQ / 128), blk, 0, stream>>>(
            atH, atL, BtH, BtL, nullptr, delta, nullptr, nullptr, MQ, DMODEL, HD, DMODEL);

        k_add_ln<<<dim3(MQ), blk, 0, stream>>>(h, delta, ln1_g + (size_t)l * DMODEL,
                                               ln1_b + (size_t)l * DMODEL, hH, hL);

        // ffn = relu(h @ w1[l] + b1[l])  [2048,3072] -> split planes directly
        k_wconv<<<dim3(DI / 32, DMODEL / 32), blk, 0, stream>>>(
            w1 + (size_t)l * DMODEL * DI, BtH, BtL, DMODEL, DI);
        k_mgemm<true, true, true><<<dim3(DI / 128, MQ / 128), blk, 0, stream>>>(
            hH, hL, BtH, BtL, b1 + (size_t)l * DI, nullptr, ffnH, ffnL, MQ, DI, DMODEL, DI);

        // delta = ffn @ w2[l] + b2[l]    [2048,768]
        k_wconv<<<dim3(DMODEL / 32, DI / 32), blk, 0, stream>>>(
            w2 + (size_t)l * DI * DMODEL, BtH, BtL, DI, DMODEL);
        k_mgemm<true, false, false><<<dim3(DMODEL / 128, MQ / 128), blk, 0, stream>>>(
            ffnH, ffnL, BtH, BtL, b2 + (size_t)l * DMODEL, delta, nullptr, nullptr,
            MQ, DMODEL, DI, DMODEL);

        k_add_ln<<<dim3(MQ), blk, 0, stream>>>(h, delta, ln2_g + (size_t)l * DMODEL,
                                               ln2_b + (size_t)l * DMODEL, hH, hL);
    }

    // out = h @ proj_w + proj_b     [2048,10000] (B cols padded to 10112 with zeros)
    k_wconv<<<dim3(NPAD_V / 32, DMODEL / 32), blk, 0, stream>>>(proj_w, BtH, BtL, DMODEL, NV);
    k_mgemm<true, false, false><<<dim3(NPAD_V / 128, MQ / 128), blk, 0, stream>>>(
        hH, hL, BtH, BtL, proj_b, out, nullptr, nullptr, MQ, NV, DMODEL, NV);
}

// Round 2
// 6495.361 us; speedup vs baseline: 1.8977x; 1.2146x over previous
//
#include <hip/hip_runtime.h>
#include <stdint.h>

#define NLAYER 12
#define NH 12
#define DH 64
#define DMODEL 768
#define DI 3072
#define NV 10000
#define QLEN 512
#define MLEN 512
#define CLEN 32
#define BSZ 4
#define KLEN (CLEN + MLEN + QLEN)   // 1056
#define MQ (QLEN * BSZ)             // 2048
#define MK (KLEN * BSZ)             // 4224
#define H3 (3 * NH * DH)            // 2304
#define HD (NH * DH)                // 768
#define NG (BSZ * NH)               // 48 batched-attention groups
#define SROW ((size_t)QLEN * KLEN)  // score elems per group: 512*1056
#define KPAD_R 1152                 // rbuf/kh rows padded to 9*128
#define NPAD_V 10112                // proj cols padded to 79*128

typedef __bf16 bf16;
typedef __bf16 bf16x8 __attribute__((ext_vector_type(8)));
typedef float f32x4 __attribute__((ext_vector_type(4)));

// async global -> LDS, 16B per lane (dest must be linear: wave base + lane*16)
__device__ __forceinline__ void gload16(const void* g, void* l) {
    __builtin_amdgcn_global_load_lds((const __attribute__((address_space(1))) void*)g,
                                     (__attribute__((address_space(3))) void*)l, 16, 0, 0);
}

// x = hi + lo split store (hi = RNE bf16(x); lo = bf16(x - hi))
__device__ __forceinline__ void split_store(float x, bf16* __restrict__ hp,
                                            bf16* __restrict__ lp, size_t off) {
    bf16 h = (bf16)x;
    hp[off] = h;
    lp[off] = (bf16)(x - (float)h);
}

// XCD-bijective + GRPM=4 row-grouped rasterization (T1 + panel-band L2 reuse)
__device__ __forceinline__ void raster(int& bx, int& by) {
    int gx = gridDim.x, gy = gridDim.y;
    int nwg = gx * gy;
    int wgid = blockIdx.y * gx + blockIdx.x;
    int q = nwg >> 3, r = nwg & 7;
    int xcd = wgid & 7, lin = wgid >> 3;
    int swz = (xcd < r ? xcd * (q + 1) : r * (q + 1) + (xcd - r) * q) + lin;
    int gsz = gx * 4;
    int grp = swz / gsz, rem = swz % gsz;
    int rows = gy - grp * 4;
    if (rows > 4) rows = 4;
    bx = rem / rows;
    by = grp * 4 + rem % rows;
}

// ---------------- embedding: h = emb[x] * sqrt(D) ----------------
__global__ __launch_bounds__(256) void k_embed(const int* __restrict__ x,
                                               const float* __restrict__ emb,
                                               float* __restrict__ h) {
    int idx = blockIdx.x * 256 + threadIdx.x;
    if (idx >= MQ * DMODEL) return;
    int row = idx / DMODEL;
    int d = idx % DMODEL;
    int tok = x[row];
    h[idx] = emb[(size_t)tok * DMODEL + d] * 27.712812921102035f;  // sqrt(768)
}

// ---------------- sinusoidal position embedding -> bf16 hi/lo planes [KPAD_R][D] ------------
__global__ __launch_bounds__(256) void k_posemb(bf16* __restrict__ rh, bf16* __restrict__ rl) {
    int idx = blockIdx.x * 256 + threadIdx.x;
    if (idx >= KPAD_R * DMODEL) return;
    int k = idx / DMODEL;
    int d = idx % DMODEL;
    float v = 0.0f;
    if (k < KLEN) {
        int pos = KLEN - 1 - k;
        int j = (d < DMODEL / 2) ? d : d - DMODEL / 2;
        double inv = exp(-((double)(2 * j) / (double)DMODEL) * log(10000.0));
        double s = (double)pos * inv;
        v = (d < DMODEL / 2) ? (float)sin(s) : (float)cos(s);
    }
    split_store(v, rh, rl, (size_t)idx);
}

// ---------------- concat [condition; mems[l]; h] -> bf16 hi/lo planes ----------------
__global__ __launch_bounds__(256) void k_concat(const float* __restrict__ cond,
                                                const float* __restrict__ mem_l,
                                                const float* __restrict__ h,
                                                bf16* __restrict__ catH,
                                                bf16* __restrict__ catL) {
    int idx = blockIdx.x * 256 + threadIdx.x;
    if (idx >= MK * DMODEL) return;
    int row = idx / DMODEL;
    int k = row / BSZ;
    float v;
    if (k < CLEN) v = cond[idx];
    else if (k < CLEN + MLEN) v = mem_l[idx - CLEN * BSZ * DMODEL];
    else v = h[idx - (CLEN + MLEN) * BSZ * DMODEL];
    split_store(v, catH, catL, (size_t)idx);
}

// ---------------- weight transpose + split: W[K][N] fp32 -> Bt_hi/lo[Npad][K] bf16 ----------
__global__ __launch_bounds__(256) void k_wconv(const float* __restrict__ W,
                                               bf16* __restrict__ Bh,
                                               bf16* __restrict__ Bl,
                                               int K, int N) {
    __shared__ float t[32][33];
    int n0 = blockIdx.x * 32, k0 = blockIdx.y * 32;
    int tc = threadIdx.x & 31, tr = threadIdx.x >> 5;
#pragma unroll
    for (int i = 0; i < 32; i += 8) {
        int n = n0 + tc;
        t[tr + i][tc] = (n < N) ? W[(size_t)(k0 + tr + i) * N + n] : 0.0f;
    }
    __syncthreads();
#pragma unroll
    for (int i = 0; i < 32; i += 8) {
        int n = n0 + tr + i;
        int k = k0 + tc;
        float x = t[tc][tr + i];
        size_t off = (size_t)n * K + k;
        bf16 h = (bf16)x;
        Bh[off] = h;
        Bl[off] = (bf16)(x - (float)h);
    }
}

// ---------------- split-bf16 MFMA GEMM: C[M,N] = A[M,K] @ B^T[N,K] (+bias)(+relu) -----------
// BM in {128, 64}; BN fixed 128. 4 waves. Rasterized (XCD-bijective + GRPM=4).
template <int BM, bool BIAS, bool RELU, bool SPLITOUT>
__global__ __launch_bounds__(256) void k_mgemm(const bf16* __restrict__ Ahi,
                                               const bf16* __restrict__ Alo,
                                               const bf16* __restrict__ Bhi,
                                               const bf16* __restrict__ Blo,
                                               const float* __restrict__ bias,
                                               float* __restrict__ C,
                                               bf16* __restrict__ Chi,
                                               bf16* __restrict__ Clo,
                                               int M, int N, int K, int ldc) {
    constexpr int MI = (BM == 128) ? 4 : 2;
    __shared__ __align__(16) bf16 As[2][BM][32];
    __shared__ __align__(16) bf16 Bs[2][128][32];
    int bx, by;
    raster(bx, by);
    int tid = threadIdx.x;
    int lane = tid & 63;
    int wave = tid >> 6;
    int bm = by * BM, bn = bx * 128;
    int wr = (wave >> 1) * (BM / 2), wc = (wave & 1) * 64;
    int fr = lane & 15;
    int fk = (lane >> 4) * 8;

    const f32x4 fzero = {0.f, 0.f, 0.f, 0.f};
    f32x4 acc[MI][4];
#pragma unroll
    for (int i = 0; i < MI; i++)
#pragma unroll
        for (int j = 0; j < 4; j++) acc[i][j] = fzero;

    int r0 = tid >> 2, p0 = (tid & 3) * 8;  // chunk tid
    int r1 = r0 + 64, p1 = p0;              // chunk tid+256

    for (int k0 = 0; k0 < K; k0 += 32) {
        if (BM == 128) {
            gload16(Ahi + (size_t)(bm + r0) * K + k0 + p0, &As[0][r0][p0]);
            gload16(Ahi + (size_t)(bm + r1) * K + k0 + p1, &As[0][r1 & (BM - 1)][p1]);
            gload16(Alo + (size_t)(bm + r0) * K + k0 + p0, &As[1][r0][p0]);
            gload16(Alo + (size_t)(bm + r1) * K + k0 + p1, &As[1][r1 & (BM - 1)][p1]);
        } else {
            gload16(Ahi + (size_t)(bm + r0) * K + k0 + p0, &As[0][r0 & (BM - 1)][p0]);
            gload16(Alo + (size_t)(bm + r0) * K + k0 + p0, &As[1][r0 & (BM - 1)][p0]);
        }
        gload16(Bhi + (size_t)(bn + r0) * K + k0 + p0, &Bs[0][r0][p0]);
        gload16(Bhi + (size_t)(bn + r1) * K + k0 + p1, &Bs[0][r1][p1]);
        gload16(Blo + (size_t)(bn + r0) * K + k0 + p0, &Bs[1][r0][p0]);
        gload16(Blo + (size_t)(bn + r1) * K + k0 + p1, &Bs[1][r1][p1]);
        __syncthreads();

        bf16x8 ah[MI], al[MI], bh[4], bl[4];
#pragma unroll
        for (int mi = 0; mi < MI; mi++) {
            ah[mi] = *(const bf16x8*)&As[0][wr + mi * 16 + fr][fk];
            al[mi] = *(const bf16x8*)&As[1][wr + mi * 16 + fr][fk];
        }
#pragma unroll
        for (int ni = 0; ni < 4; ni++) {
            bh[ni] = *(const bf16x8*)&Bs[0][wc + ni * 16 + fr][fk];
            bl[ni] = *(const bf16x8*)&Bs[1][wc + ni * 16 + fr][fk];
        }
#pragma unroll
        for (int mi = 0; mi < MI; mi++)
#pragma unroll
            for (int ni = 0; ni < 4; ni++) {
                acc[mi][ni] = __builtin_amdgcn_mfma_f32_16x16x32_bf16(ah[mi], bh[ni], acc[mi][ni], 0, 0, 0);
                acc[mi][ni] = __builtin_amdgcn_mfma_f32_16x16x32_bf16(ah[mi], bl[ni], acc[mi][ni], 0, 0, 0);
                acc[mi][ni] = __builtin_amdgcn_mfma_f32_16x16x32_bf16(al[mi], bh[ni], acc[mi][ni], 0, 0, 0);
            }
        __syncthreads();
    }

#pragma unroll
    for (int mi = 0; mi < MI; mi++) {
        int rowb = bm + wr + mi * 16 + (lane >> 4) * 4;
#pragma unroll
        for (int ni = 0; ni < 4; ni++) {
            int col = bn + wc + ni * 16 + fr;
            if (col >= N) continue;
            float bv = BIAS ? bias[col] : 0.0f;
#pragma unroll
            for (int r = 0; r < 4; r++) {
                int row = rowb + r;
                if (row >= M) continue;
                float xv = acc[mi][ni][r] + bv;
                if (RELU) xv = fmaxf(xv, 0.0f);
                size_t off = (size_t)row * ldc + col;
                if (SPLITOUT) {
                    bf16 hh = (bf16)xv;
                    Chi[off] = hh;
                    Clo[off] = (bf16)(xv - (float)hh);
                } else {
                    C[off] = xv;
                }
            }
        }
    }
}

// ---------------- q prep -> bf16 hi/lo planes [g][512][64] ----------------
__global__ __launch_bounds__(256) void k_qprep(const float* __restrict__ heads,
                                               const float* __restrict__ rwb,
                                               const float* __restrict__ rrb,
                                               bf16* __restrict__ qwH, bf16* __restrict__ qwL,
                                               bf16* __restrict__ qrH, bf16* __restrict__ qrL) {
    int idx = blockIdx.x * 256 + threadIdx.x;
    if (idx >= NG * QLEN * DH) return;
    int g = idx >> 15;
    int rem = idx & 32767;
    int i = rem >> 6;
    int d = rem & 63;
    int b = g / NH, n = g % NH;
    float q = heads[((size_t)((CLEN + MLEN + i) * BSZ + b)) * H3 + n * DH + d];
    split_store(q + rwb[n * DH + d], qwH, qwL, (size_t)idx);
    split_store(q + rrb[n * DH + d], qrH, qrL, (size_t)idx);
}

// ---------------- K heads -> grouped planes [gc][1152][64] (rows >= 1056 zero) --------------
__global__ __launch_bounds__(256) void k_kconv(const float* __restrict__ heads,
                                               bf16* __restrict__ khH, bf16* __restrict__ khL,
                                               int g0, int ngc) {
    int idx = blockIdx.x * 256 + threadIdx.x;
    if (idx >= ngc * KPAD_R * DH) return;
    int gl = idx / (KPAD_R * DH);
    int rem = idx % (KPAD_R * DH);
    int j = rem >> 6, d = rem & 63;
    int g = g0 + gl, b = g / NH, n = g % NH;
    float v = (j < KLEN) ? heads[(size_t)(j * BSZ + b) * H3 + HD + n * DH + d] : 0.0f;
    split_store(v, khH, khL, (size_t)idx);
}

// ---------------- V heads -> transposed planes vt[gc][64][1056] ----------------
__global__ __launch_bounds__(256) void k_vtconv(const float* __restrict__ heads,
                                                bf16* __restrict__ vtH, bf16* __restrict__ vtL,
                                                int g0) {
    __shared__ float t[32][33];
    int gl = blockIdx.z;
    int g = g0 + gl, b = g / NH, n = g % NH;
    int j0 = blockIdx.x * 32, d0 = blockIdx.y * 32;
    int tc = threadIdx.x & 31, tr = threadIdx.x >> 5;
#pragma unroll
    for (int i = 0; i < 32; i += 8)
        t[tr + i][tc] = heads[(size_t)((j0 + tr + i) * BSZ + b) * H3 + 2 * HD + n * DH + d0 + tc];
    __syncthreads();
#pragma unroll
    for (int i = 0; i < 32; i += 8)
        split_store(t[tc][tr + i], vtH, vtL,
                    ((size_t)gl * DH + d0 + tr + i) * KLEN + j0 + tc);
}

// ---------------- batched score GEMM (MFMA, split-bf16), K=64 ----------------
// SHIFT=false: sAc[gl][i][t]  = qw . kh   (t < 1056)
// SHIFT=true : sAc[gl][i][t-511+i] += qr . rk  (rel_shift scatter-add)
template <bool SHIFT>
__global__ __launch_bounds__(256) void k_score(const bf16* __restrict__ QH,
                                               const bf16* __restrict__ QL,
                                               const bf16* __restrict__ KHp,
                                               const bf16* __restrict__ KLp,
                                               float* __restrict__ sAc,
                                               int g0) {
    int gl = blockIdx.z;
    int g = g0 + gl;
    int n = g % NH;
    const bf16* Ah = QH + (size_t)g * QLEN * DH;
    const bf16* Al = QL + (size_t)g * QLEN * DH;
    const bf16 *Bh, *Bl;
    int ldb;
    if (SHIFT) { Bh = KHp + n * DH; Bl = KLp + n * DH; ldb = HD; }
    else { Bh = KHp + (size_t)gl * KPAD_R * DH; Bl = KLp + (size_t)gl * KPAD_R * DH; ldb = DH; }
    float* C = sAc + (size_t)gl * SROW;

    __shared__ __align__(16) bf16 As[2][128][32];
    __shared__ __align__(16) bf16 Bs[2][128][32];
    int tid = threadIdx.x;
    int lane = tid & 63;
    int wave = tid >> 6;
    int bm = blockIdx.y * 128, bn = blockIdx.x * 128;
    int wr = (wave >> 1) * 64, wc = (wave & 1) * 64;
    int fr = lane & 15;
    int fk = (lane >> 4) * 8;

    const f32x4 fzero = {0.f, 0.f, 0.f, 0.f};
    f32x4 acc[4][4];
#pragma unroll
    for (int i = 0; i < 4; i++)
#pragma unroll
        for (int j = 0; j < 4; j++) acc[i][j] = fzero;

    int r0 = tid >> 2, p0 = (tid & 3) * 8;
    int r1 = r0 + 64, p1 = p0;

#pragma unroll
    for (int k0 = 0; k0 < DH; k0 += 32) {
        gload16(Ah + (size_t)(bm + r0) * DH + k0 + p0, &As[0][r0][p0]);
        gload16(Ah + (size_t)(bm + r1) * DH + k0 + p1, &As[0][r1][p1]);
        gload16(Al + (size_t)(bm + r0) * DH + k0 + p0, &As[1][r0][p0]);
        gload16(Al + (size_t)(bm + r1) * DH + k0 + p1, &As[1][r1][p1]);
        gload16(Bh + (size_t)(bn + r0) * ldb + k0 + p0, &Bs[0][r0][p0]);
        gload16(Bh + (size_t)(bn + r1) * ldb + k0 + p1, &Bs[0][r1][p1]);
        gload16(Bl + (size_t)(bn + r0) * ldb + k0 + p0, &Bs[1][r0][p0]);
        gload16(Bl + (size_t)(bn + r1) * ldb + k0 + p1, &Bs[1][r1][p1]);
        __syncthreads();

        bf16x8 ah[4], al[4], bh[4], bl[4];
#pragma unroll
        for (int mi = 0; mi < 4; mi++) {
            ah[mi] = *(const bf16x8*)&As[0][wr + mi * 16 + fr][fk];
            al[mi] = *(const bf16x8*)&As[1][wr + mi * 16 + fr][fk];
        }
#pragma unroll
        for (int ni = 0; ni < 4; ni++) {
            bh[ni] = *(const bf16x8*)&Bs[0][wc + ni * 16 + fr][fk];
            bl[ni] = *(const bf16x8*)&Bs[1][wc + ni * 16 + fr][fk];
        }
#pragma unroll
        for (int mi = 0; mi < 4; mi++)
#pragma unroll
            for (int ni = 0; ni < 4; ni++) {
                acc[mi][ni] = __builtin_amdgcn_mfma_f32_16x16x32_bf16(ah[mi], bh[ni], acc[mi][ni], 0, 0, 0);
                acc[mi][ni] = __builtin_amdgcn_mfma_f32_16x16x32_bf16(ah[mi], bl[ni], acc[mi][ni], 0, 0, 0);
                acc[mi][ni] = __builtin_amdgcn_mfma_f32_16x16x32_bf16(al[mi], bh[ni], acc[mi][ni], 0, 0, 0);
            }
        __syncthreads();
    }

#pragma unroll
    for (int mi = 0; mi < 4; mi++) {
        int rowb = bm + wr + mi * 16 + (lane >> 4) * 4;
#pragma unroll
        for (int ni = 0; ni < 4; ni++) {
            int t = bn + wc + ni * 16 + fr;
            if (t >= KLEN) continue;
#pragma unroll
            for (int r = 0; r < 4; r++) {
                int i = rowb + r;
                if (SHIFT) {
                    int j = t - (QLEN - 1) + i;
                    if (j >= 0) C[(size_t)i * KLEN + j] += acc[mi][ni][r];
                } else {
                    C[(size_t)i * KLEN + t] = acc[mi][ni][r];
                }
            }
        }
    }
}

// ---------------- masked softmax: read fp32 scores, write bf16 probs (tail zero) ------------
__global__ __launch_bounds__(256) void k_softmax_p(const float* __restrict__ sAc,
                                                   bf16* __restrict__ P) {
    __shared__ float red[256];
    int i = blockIdx.x;
    int gl = blockIdx.y;
    int tid = threadIdx.x;
    const float* row = sAc + (size_t)gl * SROW + (size_t)i * KLEN;
    bf16* pr = P + (size_t)gl * SROW + (size_t)i * KLEN;
    int len = i + CLEN + MLEN + 1;
    float v[5];
    int cnt = 0;
    float mx = -1e30f;
    for (int j = tid; j < len; j += 256) {
        float s = row[j] * 0.125f;
        v[cnt++] = s;
        mx = fmaxf(mx, s);
    }
    red[tid] = mx;
    __syncthreads();
    for (int st = 128; st > 0; st >>= 1) {
        if (tid < st) red[tid] = fmaxf(red[tid], red[tid + st]);
        __syncthreads();
    }
    float smax = red[0];
    __syncthreads();
    float sum = 0.f;
    cnt = 0;
    for (int j = tid; j < len; j += 256) {
        float e = __expf(v[cnt] - smax);
        v[cnt] = e;
        sum += e;
        cnt++;
    }
    red[tid] = sum;
    __syncthreads();
    for (int st = 128; st > 0; st >>= 1) {
        if (tid < st) red[tid] += red[tid + st];
        __syncthreads();
    }
    float inv = 1.0f / red[0];
    cnt = 0;
    for (int j = tid; j < len; j += 256) pr[j] = (bf16)(v[cnt++] * inv);
    for (int j = tid; j < KLEN; j += 256)
        if (j >= len) pr[j] = (bf16)0.0f;
}

// ---------------- batched AV GEMM (MFMA): attnb = P @ V^T^T, K=1056 ----------------
// A = P [512][1056] (hi-only), B = vt[64][1056] hi/lo. Tile 64x64, 4 waves of 16 rows.
__global__ __launch_bounds__(256) void k_av(const bf16* __restrict__ P,
                                            const bf16* __restrict__ VH,
                                            const bf16* __restrict__ VL,
                                            bf16* __restrict__ atH,
                                            bf16* __restrict__ atL,
                                            int g0) {
    int gl = blockIdx.z;
    int g = g0 + gl;
    int b = g / NH, n = g % NH;
    const bf16* Ap = P + (size_t)gl * SROW;
    const bf16* Vh = VH + (size_t)gl * DH * KLEN;
    const bf16* Vl = VL + (size_t)gl * DH * KLEN;
    __shared__ __align__(16) bf16 As[64][32];
    __shared__ __align__(16) bf16 Bs[2][64][32];
    int tid = threadIdx.x;
    int lane = tid & 63;
    int wave = tid >> 6;
    int bm = blockIdx.y * 64;
    int fr = lane & 15;
    int fk = (lane >> 4) * 8;
    const f32x4 fzero = {0.f, 0.f, 0.f, 0.f};
    f32x4 acc[4] = {fzero, fzero, fzero, fzero};
    int ra = tid >> 2, pa = (tid & 3) * 8;

    for (int k0 = 0; k0 < KLEN; k0 += 32) {
        gload16(Ap + (size_t)(bm + ra) * KLEN + k0 + pa, &As[ra][pa]);
        gload16(Vh + (size_t)ra * KLEN + k0 + pa, &Bs[0][ra][pa]);
        gload16(Vl + (size_t)ra * KLEN + k0 + pa, &Bs[1][ra][pa]);
        __syncthreads();
        bf16x8 a = *(const bf16x8*)&As[wave * 16 + fr][fk];
#pragma unroll
        for (int ni = 0; ni < 4; ni++) {
            bf16x8 bh = *(const bf16x8*)&Bs[0][ni * 16 + fr][fk];
            bf16x8 bl = *(const bf16x8*)&Bs[1][ni * 16 + fr][fk];
            acc[ni] = __builtin_amdgcn_mfma_f32_16x16x32_bf16(a, bh, acc[ni], 0, 0, 0);
            acc[ni] = __builtin_amdgcn_mfma_f32_16x16x32_bf16(a, bl, acc[ni], 0, 0, 0);
        }
        __syncthreads();
    }

#pragma unroll
    for (int ni = 0; ni < 4; ni++) {
        int d = ni * 16 + fr;
#pragma unroll
        for (int r = 0; r < 4; r++) {
            int i = bm + wave * 16 + (lane >> 4) * 4 + r;
            size_t off = (size_t)(i * BSZ + b) * HD + n * DH + d;
            split_store(acc[ni][r], atH, atL, off);
        }
    }
}

// ---------------- h = LN(h + delta); also emit bf16 hi/lo planes of h ----------------
__global__ __launch_bounds__(256) void k_add_ln(float* __restrict__ h,
                                                const float* __restrict__ delta,
                                                const float* __restrict__ g,
                                                const float* __restrict__ bta,
                                                bf16* __restrict__ hH,
                                                bf16* __restrict__ hL) {
    __shared__ float xs[DMODEL];
    __shared__ float red[256];
    int row = blockIdx.x;
    int tid = threadIdx.x;
    float* hr = h + (size_t)row * DMODEL;
    const float* dr = delta + (size_t)row * DMODEL;
    float s = 0.f;
    for (int d = tid; d < DMODEL; d += 256) {
        float v = hr[d] + dr[d];
        xs[d] = v;
        s += v;
    }
    red[tid] = s;
    __syncthreads();
    for (int st = 128; st > 0; st >>= 1) {
        if (tid < st) red[tid] += red[tid + st];
        __syncthreads();
    }
    float mean = red[0] * (1.0f / DMODEL);
    __syncthreads();
    float v2 = 0.f;
    for (int d = tid; d < DMODEL; d += 256) {
        float t = xs[d] - mean;
        v2 += t * t;
    }
    red[tid] = v2;
    __syncthreads();
    for (int st = 128; st > 0; st >>= 1) {
        if (tid < st) red[tid] += red[tid + st];
        __syncthreads();
    }
    float inv = rsqrtf(red[0] * (1.0f / DMODEL) + 1e-5f);
    for (int d = tid; d < DMODEL; d += 256) {
        float y = (xs[d] - mean) * inv * g[d] + bta[d];
        hr[d] = y;
        split_store(y, hH, hL, (size_t)row * DMODEL + d);
    }
}

extern "C" void kernel_launch(void* const* d_in, const int* in_sizes, int n_in,
                              void* d_out, int out_size, void* d_ws, size_t ws_size,
                              hipStream_t stream) {
    const int* x = (const int*)d_in[0];
    const float* condition = (const float*)d_in[1];
    const float* mems = (const float*)d_in[2];
    const float* emb = (const float*)d_in[3];
    const float* qkv_w = (const float*)d_in[4];
    const float* r_net_w = (const float*)d_in[5];
    const float* o_w = (const float*)d_in[6];
    const float* ln1_g = (const float*)d_in[7];
    const float* ln1_b = (const float*)d_in[8];
    const float* w1 = (const float*)d_in[9];
    const float* b1 = (const float*)d_in[10];
    const float* w2 = (const float*)d_in[11];
    const float* b2 = (const float*)d_in[12];
    const float* ln2_g = (const float*)d_in[13];
    const float* ln2_b = (const float*)d_in[14];
    const float* r_w_bias = (const float*)d_in[15];
    const float* r_r_bias = (const float*)d_in[16];
    const float* proj_w = (const float*)d_in[17];
    const float* proj_b = (const float*)d_in[18];
    float* out = (float*)d_out;

    // ---- fixed fp32 region ----
    float* ws = (float*)d_ws;
    float* h = ws;                                    // 2048*768
    float* heads = h + (size_t)MQ * DMODEL;           // 4224*2304
    float* delta = heads + (size_t)MK * H3;           // 2048*768

    // ---- persistent bf16 planes ----
    bf16* pb = (bf16*)(delta + (size_t)MQ * DMODEL);
    bf16* rbH = pb; pb += (size_t)KPAD_R * DMODEL;
    bf16* rbL = pb; pb += (size_t)KPAD_R * DMODEL;
    bf16* atH = pb; pb += (size_t)MQ * HD;
    bf16* atL = pb; pb += (size_t)MQ * HD;
    bf16* qwH = pb; pb += (size_t)NG * QLEN * DH;
    bf16* qwL = pb; pb += (size_t)NG * QLEN * DH;
    bf16* qrH = pb; pb += (size_t)NG * QLEN * DH;
    bf16* qrL = pb; pb += (size_t)NG * QLEN * DH;
    bf16* rkH = pb; pb += (size_t)KPAD_R * DMODEL;
    bf16* rkL = pb; pb += (size_t)KPAD_R * DMODEL;

    // ---- alias region R: (b) GEMM-side planes XOR (a) attention chunk buffers ----
    bf16* R = pb;
    bf16* BtH = R;
    bf16* BtL = BtH + (size_t)NPAD_V * DMODEL;
    bf16* ffnH = BtL + (size_t)NPAD_V * DMODEL;
    bf16* ffnL = ffnH + (size_t)MQ * DI;
    bf16* catH = ffnL + (size_t)MQ * DI;
    bf16* catL = catH + (size_t)MK * DMODEL;
    bf16* hH = catL + (size_t)MK * DMODEL;
    bf16* hL = hH + (size_t)MQ * DMODEL;

    // chunked attention buffers overlay the same region
    size_t fixed_bytes = (size_t)((char*)R - (char*)d_ws);
    size_t chunk48 = (size_t)48 * (SROW * 6 + KPAD_R * DH * 4 + DH * KLEN * 4);
    int NGC = (ws_size >= fixed_bytes + chunk48) ? 48 : 24;
    float* sAc = (float*)R;
    bf16* Pc = (bf16*)(sAc + (size_t)NGC * SROW);
    bf16* khH = Pc + (size_t)NGC * SROW;
    bf16* khL = khH + (size_t)NGC * KPAD_R * DH;
    bf16* vtH = khL + (size_t)NGC * KPAD_R * DH;
    bf16* vtL = vtH + (size_t)NGC * DH * KLEN;

    dim3 blk(256);
    k_embed<<<dim3((MQ * DMODEL + 255) / 256), blk, 0, stream>>>(x, emb, h);
    k_posemb<<<dim3((KPAD_R * DMODEL + 255) / 256), blk, 0, stream>>>(rbH, rbL);

    for (int l = 0; l < NLAYER; l++) {
        k_concat<<<dim3((MK * DMODEL + 255) / 256), blk, 0, stream>>>(
            condition, mems + (size_t)l * MLEN * BSZ * DMODEL, h, catH, catL);

        // heads = cat @ qkv_w[l]    [4224,2304]
        k_wconv<<<dim3(H3 / 32, DMODEL / 32), blk, 0, stream>>>(
            qkv_w + (size_t)l * DMODEL * H3, BtH, BtL, DMODEL, H3);
        k_mgemm<128, false, false, false><<<dim3(H3 / 128, MK / 128), blk, 0, stream>>>(
            catH, catL, BtH, BtL, nullptr, heads, nullptr, nullptr, MK, H3, DMODEL, H3);

        // rk = r @ r_net_w[l]  -> split planes [1152][768] (pad rows produce zeros)
        k_wconv<<<dim3(HD / 32, DMODEL / 32), blk, 0, stream>>>(
            r_net_w + (size_t)l * DMODEL * HD, BtH, BtL, DMODEL, HD);
        k_mgemm<64, false, false, true><<<dim3(HD / 128, KPAD_R / 64), blk, 0, stream>>>(
            rbH, rbL, BtH, BtL, nullptr, nullptr, rkH, rkL, KPAD_R, HD, DMODEL, HD);

        // q + biases -> bf16 planes
        k_qprep<<<dim3((NG * QLEN * DH + 255) / 256), blk, 0, stream>>>(
            heads, r_w_bias, r_r_bias, qwH, qwL, qrH, qrL);

        // ---- attention, chunked over groups ----
        for (int g0 = 0; g0 < NG; g0 += NGC) {
            k_kconv<<<dim3((NGC * KPAD_R * DH + 255) / 256), blk, 0, stream>>>(
                heads, khH, khL, g0, NGC);
            k_vtconv<<<dim3(KLEN / 32, DH / 32, NGC), blk, 0, stream>>>(heads, vtH, vtL, g0);
            k_score<false><<<dim3(KPAD_R / 128, QLEN / 128, NGC), blk, 0, stream>>>(
                qwH, qwL, khH, khL, sAc, g0);
            k_score<true><<<dim3(KPAD_R / 128, QLEN / 128, NGC), blk, 0, stream>>>(
                qrH, qrL, rkH, rkL, sAc, g0);
            k_softmax_p<<<dim3(QLEN, NGC), blk, 0, stream>>>(sAc, Pc);
            k_av<<<dim3(1, QLEN / 64, NGC), blk, 0, stream>>>(Pc, vtH, vtL, atH, atL, g0);
        }

        // delta = attnb @ o_w[l]    [2048,768]
        k_wconv<<<dim3(DMODEL / 32, HD / 32), blk, 0, stream>>>(
            o_w + (size_t)l * HD * DMODEL, BtH, BtL, HD, DMODEL);
        k_mgemm<64, false, false, false><<<dim3(DMODEL / 128, MQ / 64), blk, 0, stream>>>(
            atH, atL, BtH, BtL, nullptr, delta, nullptr, nullptr, MQ, DMODEL, HD, DMODEL);

        k_add_ln<<<dim3(MQ), blk, 0, stream>>>(h, delta, ln1_g + (size_t)l * DMODEL,
                                               ln1_b + (size_t)l * DMODEL, hH, hL);

        // ffn = relu(h @ w1[l] + b1[l])  [2048,3072] -> split planes
        k_wconv<<<dim3(DI / 32, DMODEL / 32), blk, 0, stream>>>(
            w1 + (size_t)l * DMODEL * DI, BtH, BtL, DMODEL, DI);
        k_mgemm<128, true, true, true><<<dim3(DI / 128, MQ / 128), blk, 0, stream>>>(
            hH, hL, BtH, BtL, b1 + (size_t)l * DI, nullptr, ffnH, ffnL, MQ, DI, DMODEL, DI);

        // delta = ffn @ w2[l] + b2[l]    [2048,768]
        k_wconv<<<dim3(DMODEL / 32, DI / 32), blk, 0, stream>>>(
            w2 + (size_t)l * DI * DMODEL, BtH, BtL, DI, DMODEL);
        k_mgemm<64, true, false, false><<<dim3(DMODEL / 128, MQ / 64), blk, 0, stream>>>(
            ffnH, ffnL, BtH, BtL, b2 + (size_t)l * DMODEL, delta, nullptr, nullptr,
            MQ, DMODEL, DI, DMODEL);

        k_add_ln<<<dim3(MQ), blk, 0, stream>>>(h, delta, ln2_g + (size_t)l * DMODEL,
                                               ln2_b + (size_t)l * DMODEL, hH, hL);
    }

    // out = h @ proj_w + proj_b     [2048,10000]
    k_wconv<<<dim3(NPAD_V / 32, DMODEL / 32), blk, 0, stream>>>(proj_w, BtH, BtL, DMODEL, NV);
    k_mgemm<128, true, false, false><<<dim3(NPAD_V / 128, MQ / 128), blk, 0, stream>>>(
        hH, hL, BtH, BtL, proj_b, out, nullptr, nullptr, MQ, NV, DMODEL, NV);
}